// Round 20
// baseline (118.434 us; speedup 1.0000x reference)
//
#include <hip/hip_runtime.h>
#include <stdint.h>

typedef _Float16 f16x8 __attribute__((ext_vector_type(8)));
typedef __bf16 bf16x8 __attribute__((ext_vector_type(8)));
typedef float f32x4 __attribute__((ext_vector_type(4)));

#define MFMA_F16(a,b,c) __builtin_amdgcn_mfma_f32_16x16x32_f16(a,b,c,0,0,0)
#define MFMA_BF16(a,b,c) __builtin_amdgcn_mfma_f32_16x16x32_bf16(a,b,c,0,0,0)
#define ALPHA 1.2011224087864498f   // sqrt(log2(e)); both operands scaled -> S in log2 domain
#define EXP2R(x) __builtin_amdgcn_exp2f(x)   // raw v_exp_f32 (args bounded by defer-max)

// ---------------- helpers ----------------
__device__ __forceinline__ uint32_t f2u(float x){ union{float f;uint32_t u;} c; c.f=x; return c.u; }
__device__ __forceinline__ float u2f(uint32_t u){ union{float f;uint32_t u;} c; c.u=u; return c.f; }

union HU8 { uint32_t u[4]; _Float16 h[8]; f16x8 v; };

// bf16 truncation split (fallback kernel)
__device__ __forceinline__ void split_pair(float x0, float x1, uint32_t& hp, uint32_t& lp){
  uint32_t u0=f2u(x0), u1=f2u(x1);
  uint32_t h0=u0&0xFFFF0000u, h1=u1&0xFFFF0000u;
  hp = (u0>>16) | h1;
  float l0 = x0 - u2f(h0), l1 = x1 - u2f(h1);
  lp = (f2u(l0)>>16) | (f2u(l1)&0xFFFF0000u);
}

// async global->LDS, 16 bytes per lane. LDS dest = wave-uniform base + lane*16.
__device__ __forceinline__ void glds16(const void* g, void* l){
  __builtin_amdgcn_global_load_lds(
      (const __attribute__((address_space(1))) uint32_t*)(uintptr_t)g,
      (__attribute__((address_space(3))) uint32_t*)(uint32_t)(uintptr_t)l,
      16, 0, 0);
}

// =====================================================================
// Pre-pass (fused K + m_k): ALPHA*x -> f16 RN plane
// =====================================================================
__global__ void kast_cvt3(const float* __restrict__ K_, const float* __restrict__ MK_,
                          uint4* __restrict__ khi, uint4* __restrict__ mkhi){
  int i = blockIdx.x*256 + threadIdx.x;     // 0..3145727
  const float* src; uint4* hi; int j;
  if (i < 2097152){ src = K_;  hi = khi;  j = i; }
  else            { src = MK_; hi = mkhi; j = i - 2097152; }
  const float4* in4 = (const float4*)src;
  float4 a = in4[(size_t)j*2], c = in4[(size_t)j*2+1];
  HU8 h;
  h.h[0]=(_Float16)(a.x*ALPHA); h.h[1]=(_Float16)(a.y*ALPHA);
  h.h[2]=(_Float16)(a.z*ALPHA); h.h[3]=(_Float16)(a.w*ALPHA);
  h.h[4]=(_Float16)(c.x*ALPHA); h.h[5]=(_Float16)(c.y*ALPHA);
  h.h[6]=(_Float16)(c.z*ALPHA); h.h[7]=(_Float16)(c.w*ALPHA);
  hi[j] = make_uint4(h.u[0],h.u[1],h.u[2],h.u[3]);
}

// =====================================================================
// v18 attn: 16-key tiles -> 19.3KB LDS -> ~6 blocks/CU resident
// (vs v16's 2.85): independent blocks interleave across barrier stalls.
// Single-barrier scheme kept: vmcnt(0) -> s_barrier -> ISSUE(nt+1) ->
// compute. 2688 blocks x 256 thr; 16 tiles x 16 keys per block.
// =====================================================================
__launch_bounds__(256, 2)
__global__ void kast_attn18(const ushort* __restrict__ khi, const ushort* __restrict__ mkhi,
                            const float* __restrict__ V_, const float* __restrict__ MV_,
                            float* __restrict__ part) {
  __shared__ uint8_t KB[2][8192];     // [buf][16 keys x 256 f16], XOR-swizzled granules
  __shared__ float vlds[768];         // 256 keys x 3 f32

  // XCD-aware decode: slice s on XCD s%8; its 48 blocks share that L2
  const int bid = blockIdx.x;          // 0..2687
  const int xcd = bid & 7;
  const int idx = bid >> 3;            // 0..335
  const int grp = idx / 48;            // 0..6
  const int sub = idx - grp*48;        // 0..47
  const int s   = xcd + 8*grp;         // slice 0..55
  const int qb  = sub & 7;             // q-block 0..7
  const int ks  = sub >> 3;            // key-split 0..5
  const int b = s / 7, t = s % 7;

  const uint8_t* kh8; const float* vbase;
  if (ks < 4){
    size_t row0 = (size_t)((b*8 + t)*1024 + ks*256);
    kh8 = (const uint8_t*)khi + row0*512;
    vbase = V_ + row0*3;
  } else {
    size_t row0 = (size_t)((b*8 + t)*512 + (ks-4)*256);
    kh8 = (const uint8_t*)mkhi + row0*512;
    vbase = MV_ + row0*3;
  }

  const int tid = threadIdx.x;
  const int w = tid >> 6, l = tid & 63;
  const int lj = l & 15, lq = l >> 4;
  const int qrow0 = qb*128 + w*32;

  // ---- stage V (256 x 3 f32) once ----
  for (int i = tid; i < 768; i += 256) vlds[i] = vbase[i];

  // ---- Q fragments: b128 loads from pre-converted plane ----
  const uint8_t* q8 = (const uint8_t*)khi + (size_t)((b*8 + t + 1)*1024)*512;
  f16x8 qh[2][8];
#pragma unroll
  for (int rt=0; rt<2; rt++){
    const uint8_t* qr = q8 + (size_t)(qrow0 + rt*16 + lj)*512 + lq*16;
#pragma unroll
    for (int kc=0; kc<8; kc++)
      qh[rt][kc] = *(const f16x8*)(qr + kc*64);
  }

  // per-lane online-softmax state (log2 domain, deferred max)
  float m[2][4], ssum[2][4], o[2][4][3];
#pragma unroll
  for (int rt=0;rt<2;rt++)
#pragma unroll
    for (int r=0;r<4;r++){
      m[rt][r]=-1e30f; ssum[rt][r]=0.f;
      o[rt][r][0]=0.f; o[rt][r][1]=0.f; o[rt][r][2]=0.f;
    }

  // DMA: 16 rows/tile, 4 waves -> 4 rows/wave = 2 glds16.
  // per-lane source row = w*4 + i*2 + (l>>5); granule sg = l&31,
  // pre-swizzled g^(row&7) -> LDS lands XOR-swizzled, dest linear.
  const int sg = l & 31;
  const int rsub = l >> 5;

  #define ISSUE_TILE(NT, P) do{                                              \
    _Pragma("unroll")                                                        \
    for (int i_=0;i_<2;i_++){                                                \
      int lrow_ = (w<<2) + (i_<<1) + rsub;                                   \
      size_t soff_ = (size_t)((NT)*16 + lrow_)*512 + (size_t)((sg ^ (lrow_&7))<<4); \
      uint32_t dbase_ = ((w<<2) + (i_<<1))*512;                              \
      glds16(kh8 + soff_, &KB[(P)][dbase_]);                                 \
    } }while(0)

  // prologue: tile 0 -> buf 0; full sync also covers V-staging ds_writes
  ISSUE_TILE(0, 0);
  __syncthreads();

  for (int nt=0; nt<16; nt++){
    const int cur = nt & 1;
    asm volatile("s_waitcnt vmcnt(0)" ::: "memory");   // my tile-nt DMA landed
    asm volatile("s_barrier" ::: "memory");            // => ALL waves' tile-nt landed;
                                                       //    all reads of buf^1 (iter nt-1) done
    if (nt < 15) ISSUE_TILE(nt+1, cur^1);              // full compute phase to land

    // ---- MFMA: S = Qh*Kh (log2 domain), 16 keys ----
    f32x4 acc[2];
    acc[0]=(f32x4){0,0,0,0}; acc[1]=(f32x4){0,0,0,0};

    const int sx = (l&7)<<4;
    const uint8_t* rb = &KB[cur][lj*512];
    __builtin_amdgcn_s_setprio(1);
#pragma unroll
    for (int kc=0;kc<8;kc++){
      int bo = (kc*64 + (lq<<4)) ^ sx;
      f16x8 bh = *(const f16x8*)(rb + bo);
      acc[0] = MFMA_F16(qh[0][kc], bh, acc[0]);
      acc[1] = MFMA_F16(qh[1][kc], bh, acc[1]);
    }
    __builtin_amdgcn_s_setprio(0);

    // ---- softmax, exp2 domain with deferred max (THR=24) + PV ----
    int c = (nt*16 + lj)*3;
    float v0=vlds[c], v1=vlds[c+1], v2=vlds[c+2];
    float need = -1e30f;
#pragma unroll
    for (int rt=0;rt<2;rt++)
#pragma unroll
      for (int r=0;r<4;r++)
        need = fmaxf(need, acc[rt][r] - m[rt][r]);
    if (need > 24.f){      // fires at tile 0 and rarely after: rescale
#pragma unroll
      for (int rt=0;rt<2;rt++)
#pragma unroll
        for (int r=0;r<4;r++){
          float mn = fmaxf(m[rt][r], acc[rt][r]);
          float sc = EXP2R(m[rt][r] - mn);
          ssum[rt][r] *= sc;
          o[rt][r][0] *= sc; o[rt][r][1] *= sc; o[rt][r][2] *= sc;
          m[rt][r] = mn;
        }
    }
#pragma unroll
    for (int rt=0;rt<2;rt++)
#pragma unroll
      for (int r=0;r<4;r++){
        float p0 = EXP2R(acc[rt][r] - m[rt][r]);
        ssum[rt][r] += p0;
        o[rt][r][0] += p0*v0;
        o[rt][r][1] += p0*v1;
        o[rt][r][2] += p0*v2;
      }
  } // nt

  // ---- merge 16 lanes (lj) per row, write partial (m,s,o) ----
#pragma unroll
  for (int rt=0;rt<2;rt++)
#pragma unroll
    for (int r=0;r<4;r++){
      float mm = m[rt][r];
      mm = fmaxf(mm, __shfl_xor(mm,1));
      mm = fmaxf(mm, __shfl_xor(mm,2));
      mm = fmaxf(mm, __shfl_xor(mm,4));
      mm = fmaxf(mm, __shfl_xor(mm,8));
      float f = EXP2R(m[rt][r]-mm);
      float sl = ssum[rt][r]*f;
      float o0=o[rt][r][0]*f, o1=o[rt][r][1]*f, o2=o[rt][r][2]*f;
      sl += __shfl_xor(sl,1); sl += __shfl_xor(sl,2); sl += __shfl_xor(sl,4); sl += __shfl_xor(sl,8);
      o0 += __shfl_xor(o0,1); o0 += __shfl_xor(o0,2); o0 += __shfl_xor(o0,4); o0 += __shfl_xor(o0,8);
      o1 += __shfl_xor(o1,1); o1 += __shfl_xor(o1,2); o1 += __shfl_xor(o1,4); o1 += __shfl_xor(o1,8);
      o2 += __shfl_xor(o2,1); o2 += __shfl_xor(o2,2); o2 += __shfl_xor(o2,4); o2 += __shfl_xor(o2,8);
      if (lj == 0){
        int prow = qrow0 + rt*16 + lq*4 + r;
        float* pp = part + ((size_t)(s*6 + ks)*1024 + prow)*5;
        pp[0]=mm; pp[1]=sl; pp[2]=o0; pp[3]=o1; pp[4]=o2;
      }
    }
  #undef ISSUE_TILE
}

// merge 6 partials per q-row (4 K-parts, 2 M-parts) -> blended output
__global__ void kast_merge6(const float* __restrict__ part, float* __restrict__ OUT_){
  int r = blockIdx.x*256 + threadIdx.x;   // 0..57343
  if (r >= 56*1024) return;
  int s = r >> 10, row = r & 1023;
  const float* p[6];
#pragma unroll
  for (int i=0;i<6;i++) p[i] = part + ((size_t)(s*6+i)*1024 + row)*5;
  // K-attn: parts 0..3
  float M1 = fmaxf(fmaxf(p[0][0], p[1][0]), fmaxf(p[2][0], p[3][0]));
  float sK = 0.f, oK0 = 0.f, oK1 = 0.f, oK2 = 0.f;
#pragma unroll
  for (int i=0;i<4;i++){
    float e = EXP2R(p[i][0]-M1);
    sK += p[i][1]*e; oK0 += p[i][2]*e; oK1 += p[i][3]*e; oK2 += p[i][4]*e;
  }
  // M-attn: parts 4..5
  float M2 = fmaxf(p[4][0], p[5][0]);
  float e0 = EXP2R(p[4][0]-M2), e1 = EXP2R(p[5][0]-M2);
  float sM = p[4][1]*e0 + p[5][1]*e1;
  float w1 = 0.8f / sK;
  float w2 = 0.2f / sM;
  float* op = OUT_ + (size_t)(s*1024 + row)*3;
  op[0] = oK0*w1 + (p[4][2]*e0 + p[5][2]*e1)*w2;
  op[1] = oK1*w1 + (p[4][3]*e0 + p[5][3]*e1)*w2;
  op[2] = oK2*w1 + (p[4][4]*e0 + p[5][4]*e1)*w2;
}

// =====================================================================
// Fallback (round-2 passing kernel) if ws too small
// =====================================================================
__launch_bounds__(256, 2)
__global__ void kast_attn_fb(const float* __restrict__ K_, const float* __restrict__ V_,
                             const float* __restrict__ MK_, const float* __restrict__ MV_,
                             float* __restrict__ OUT_) {
  __shared__ char KhB[64*512];
  __shared__ char KlB[64*512];
  __shared__ float vlds[192];

  const int bid = blockIdx.x;
  const int s  = ((bid>>6)<<3) | (bid & 7);
  const int qb = (bid>>3) & 7;
  const int b = s / 7, t = s % 7;
  const float* qptr = K_ + (size_t)((b*8 + t + 1) * 1024) * 256;
  const float* k1   = K_ + (size_t)((b*8 + t) * 1024) * 256;
  const float* v1   = V_ + (size_t)((b*8 + t) * 1024) * 3;
  const float* k2   = MK_ + (size_t)((b*8 + t) * 512) * 256;
  const float* v2   = MV_ + (size_t)((b*8 + t) * 512) * 3;
  float* outp = OUT_ + (size_t)((b*7 + t) * 1024) * 3;

  const int tid = threadIdx.x;
  const int w = tid >> 6, l = tid & 63;
  const int lj = l & 15, lq = l >> 4;
  const int qrow0 = qb*128 + w*32;

  bf16x8 qh[2][8], ql[2][8];
#pragma unroll
  for (int rt=0; rt<2; rt++){
    const float* qr = qptr + (size_t)(qrow0 + rt*16 + lj)*256 + lq*8;
#pragma unroll
    for (int kc=0; kc<8; kc++){
      float4 a = *(const float4*)(qr + kc*32);
      float4 c = *(const float4*)(qr + kc*32 + 4);
      union { uint32_t d[4]; bf16x8 v; } hh, ll;
      split_pair(a.x, a.y, hh.d[0], ll.d[0]);
      split_pair(a.z, a.w, hh.d[1], ll.d[1]);
      split_pair(c.x, c.y, hh.d[2], ll.d[2]);
      split_pair(c.z, c.w, hh.d[3], ll.d[3]);
      qh[rt][kc]=hh.v; ql[rt][kc]=ll.v;
    }
  }

  for (int ph=0; ph<2; ph++){
    const float* ks = ph ? k2 : k1;
    const float* vs = ph ? v2 : v1;
    const int ntiles = ph ? 8 : 16;
    float m[2][4], ssum[2][4], o[2][4][3];
#pragma unroll
    for (int rt=0;rt<2;rt++)
#pragma unroll
      for (int r=0;r<4;r++){
        m[rt][r]=-1e30f; ssum[rt][r]=0.f;
        o[rt][r][0]=0.f; o[rt][r][1]=0.f; o[rt][r][2]=0.f;
      }

    for (int nt=0; nt<ntiles; nt++){
      __syncthreads();
      const float* kt = ks + (size_t)nt*64*256;
#pragma unroll 4
      for (int i=0;i<16;i++){
        int f4i = tid + i*256;
        int row = f4i >> 6;
        int col4 = f4i & 63;
        float4 x = *(const float4*)(kt + row*256 + col4*4);
        uint32_t hp0,lp0,hp1,lp1;
        split_pair(x.x,x.y,hp0,lp0);
        split_pair(x.z,x.w,hp1,lp1);
        int boff = row*512 + ((col4*8) ^ ((row&7)<<4));
        *(uint2*)(KhB + boff) = make_uint2(hp0,hp1);
        *(uint2*)(KlB + boff) = make_uint2(lp0,lp1);
      }
      if (tid < 192) vlds[tid] = vs[nt*192 + tid];
      __syncthreads();

      f32x4 acc[2][4];
#pragma unroll
      for (int rt=0;rt<2;rt++)
#pragma unroll
        for (int ct=0;ct<4;ct++)
          acc[rt][ct] = (f32x4){0.f,0.f,0.f,0.f};

      const int sx = (l&7)<<4;
#pragma unroll
      for (int ct=0;ct<4;ct++){
        const char* rbh = KhB + (ct*16 + lj)*512;
        const char* rbl = KlB + (ct*16 + lj)*512;
#pragma unroll
        for (int kc=0;kc<8;kc++){
          int bo = (kc*64 + (lq<<4)) ^ sx;
          bf16x8 bh = *(const bf16x8*)(rbh + bo);
          bf16x8 bl = *(const bf16x8*)(rbl + bo);
          acc[0][ct] = MFMA_BF16(qh[0][kc], bh, acc[0][ct]);
          acc[1][ct] = MFMA_BF16(qh[1][kc], bh, acc[1][ct]);
          acc[0][ct] = MFMA_BF16(qh[0][kc], bl, acc[0][ct]);
          acc[1][ct] = MFMA_BF16(qh[1][kc], bl, acc[1][ct]);
          acc[0][ct] = MFMA_BF16(ql[0][kc], bh, acc[0][ct]);
          acc[1][ct] = MFMA_BF16(ql[1][kc], bh, acc[1][ct]);
        }
      }

      float vv[4][3];
#pragma unroll
      for (int ct=0;ct<4;ct++){
        int c = (ct*16 + lj)*3;
        vv[ct][0]=vlds[c]; vv[ct][1]=vlds[c+1]; vv[ct][2]=vlds[c+2];
      }
#pragma unroll
      for (int rt=0;rt<2;rt++)
#pragma unroll
        for (int r=0;r<4;r++){
          float s0=acc[rt][0][r], s1=acc[rt][1][r], s2=acc[rt][2][r], s3=acc[rt][3][r];
          float tmax = fmaxf(fmaxf(s0,s1),fmaxf(s2,s3));
          float mo = m[rt][r];
          float mn = fmaxf(mo, tmax);
          float sc = __expf(mo - mn);
          float p0=__expf(s0-mn), p1=__expf(s1-mn), p2=__expf(s2-mn), p3=__expf(s3-mn);
          ssum[rt][r] = ssum[rt][r]*sc + ((p0+p1)+(p2+p3));
          o[rt][r][0] = o[rt][r][0]*sc + (p0*vv[0][0]+p1*vv[1][0]) + (p2*vv[2][0]+p3*vv[3][0]);
          o[rt][r][1] = o[rt][r][1]*sc + (p0*vv[0][1]+p1*vv[1][1]) + (p2*vv[2][1]+p3*vv[3][1]);
          o[rt][r][2] = o[rt][r][2]*sc + (p0*vv[0][2]+p1*vv[1][2]) + (p2*vv[2][2]+p3*vv[3][2]);
          m[rt][r]=mn;
        }
    }

    const float coef = ph ? 0.2f : 0.8f;
#pragma unroll
    for (int rt=0;rt<2;rt++)
#pragma unroll
      for (int r=0;r<4;r++){
        float mm = m[rt][r];
        mm = fmaxf(mm, __shfl_xor(mm,1));
        mm = fmaxf(mm, __shfl_xor(mm,2));
        mm = fmaxf(mm, __shfl_xor(mm,4));
        mm = fmaxf(mm, __shfl_xor(mm,8));
        float f = __expf(m[rt][r]-mm);
        float sl = ssum[rt][r]*f;
        float o0=o[rt][r][0]*f, o1=o[rt][r][1]*f, o2=o[rt][r][2]*f;
        sl += __shfl_xor(sl,1); sl += __shfl_xor(sl,2); sl += __shfl_xor(sl,4); sl += __shfl_xor(sl,8);
        o0 += __shfl_xor(o0,1); o0 += __shfl_xor(o0,2); o0 += __shfl_xor(o0,4); o0 += __shfl_xor(o0,8);
        o1 += __shfl_xor(o1,1); o1 += __shfl_xor(o1,2); o1 += __shfl_xor(o1,4); o1 += __shfl_xor(o1,8);
        o2 += __shfl_xor(o2,1); o2 += __shfl_xor(o2,2); o2 += __shfl_xor(o2,4); o2 += __shfl_xor(o2,8);
        if (lj == 0){
          int row = qrow0 + rt*16 + lq*4 + r;
          float* op = outp + (size_t)row*3;
          float invs = coef / sl;
          if (ph==0){ op[0]=o0*invs; op[1]=o1*invs; op[2]=o2*invs; }
          else      { op[0]+=o0*invs; op[1]+=o1*invs; op[2]+=o2*invs; }
        }
      }
  }
}

// ground truth = v[:,1:] (second output, exact copy)
__global__ void kast_gt(const float* __restrict__ V_, float* __restrict__ OUT_){
  int s = blockIdx.x; int b = s/7, t = s%7;
  const float4* src = (const float4*)(V_ + (size_t)(b*8+t+1)*3072);
  float4* dst = (float4*)(OUT_ + 172032 + (size_t)s*3072);
  for (int i=threadIdx.x; i<768; i+=256) dst[i] = src[i];
}

extern "C" void kernel_launch(void* const* d_in, const int* in_sizes, int n_in,
                              void* d_out, int out_size, void* d_ws, size_t ws_size,
                              hipStream_t stream) {
  (void)in_sizes; (void)n_in; (void)out_size;
  const float* K_  = (const float*)d_in[0];
  const float* V_  = (const float*)d_in[1];
  const float* MK_ = (const float*)d_in[2];
  const float* MV_ = (const float*)d_in[3];
  float* out = (float*)d_out;

  // ws layout (bytes): khi 33.55M | mkhi 16.78M | partials 6.88M
  const size_t NEED = 57212928;
  if (ws_size >= NEED){
    uint8_t* w8 = (uint8_t*)d_ws;
    ushort* khi  = (ushort*)(w8);
    ushort* mkhi = (ushort*)(w8 + 33554432);
    float*  part = (float*)(w8 + 50331648);
    hipLaunchKernelGGL(kast_cvt3, dim3(12288), dim3(256), 0, stream, K_, MK_,
                       (uint4*)khi, (uint4*)mkhi);
    hipLaunchKernelGGL(kast_attn18, dim3(2688), dim3(256), 0, stream, khi, mkhi, V_, MV_, part);
    hipLaunchKernelGGL(kast_merge6, dim3(224),  dim3(256), 0, stream, part, out);
  } else {
    hipLaunchKernelGGL(kast_attn_fb, dim3(448), dim3(256), 0, stream, K_, V_, MK_, MV_, out);
  }
  hipLaunchKernelGGL(kast_gt, dim3(56), dim3(256), 0, stream, V_, out);
}

// Round 21
// 112.797 us; speedup vs baseline: 1.0500x; 1.0500x over previous
//
#include <hip/hip_runtime.h>
#include <stdint.h>

typedef _Float16 f16x8 __attribute__((ext_vector_type(8)));
typedef __bf16 bf16x8 __attribute__((ext_vector_type(8)));
typedef float f32x4 __attribute__((ext_vector_type(4)));

#define MFMA_F16(a,b,c) __builtin_amdgcn_mfma_f32_16x16x32_f16(a,b,c,0,0,0)
#define MFMA_BF16(a,b,c) __builtin_amdgcn_mfma_f32_16x16x32_bf16(a,b,c,0,0,0)
#define ALPHA 1.2011224087864498f   // sqrt(log2(e)); both operands scaled -> S in log2 domain
#define EXP2R(x) __builtin_amdgcn_exp2f(x)   // raw v_exp_f32 (args bounded by defer-max)

// ---------------- helpers ----------------
__device__ __forceinline__ uint32_t f2u(float x){ union{float f;uint32_t u;} c; c.f=x; return c.u; }
__device__ __forceinline__ float u2f(uint32_t u){ union{float f;uint32_t u;} c; c.u=u; return c.f; }

union HU8 { uint32_t u[4]; _Float16 h[8]; f16x8 v; };

// bf16 truncation split (fallback kernel)
__device__ __forceinline__ void split_pair(float x0, float x1, uint32_t& hp, uint32_t& lp){
  uint32_t u0=f2u(x0), u1=f2u(x1);
  uint32_t h0=u0&0xFFFF0000u, h1=u1&0xFFFF0000u;
  hp = (u0>>16) | h1;
  float l0 = x0 - u2f(h0), l1 = x1 - u2f(h1);
  lp = (f2u(l0)>>16) | (f2u(l1)&0xFFFF0000u);
}

// async global->LDS, 16 bytes per lane. LDS dest = wave-uniform base + lane*16.
__device__ __forceinline__ void glds16(const void* g, void* l){
  __builtin_amdgcn_global_load_lds(
      (const __attribute__((address_space(1))) uint32_t*)(uintptr_t)g,
      (__attribute__((address_space(3))) uint32_t*)(uint32_t)(uintptr_t)l,
      16, 0, 0);
}

// =====================================================================
// Pre-pass (fused K + m_k): ALPHA*x -> f16 RN plane
// =====================================================================
__global__ void kast_cvt3(const float* __restrict__ K_, const float* __restrict__ MK_,
                          uint4* __restrict__ khi, uint4* __restrict__ mkhi){
  int i = blockIdx.x*256 + threadIdx.x;     // 0..3145727
  const float* src; uint4* hi; int j;
  if (i < 2097152){ src = K_;  hi = khi;  j = i; }
  else            { src = MK_; hi = mkhi; j = i - 2097152; }
  const float4* in4 = (const float4*)src;
  float4 a = in4[(size_t)j*2], c = in4[(size_t)j*2+1];
  HU8 h;
  h.h[0]=(_Float16)(a.x*ALPHA); h.h[1]=(_Float16)(a.y*ALPHA);
  h.h[2]=(_Float16)(a.z*ALPHA); h.h[3]=(_Float16)(a.w*ALPHA);
  h.h[4]=(_Float16)(c.x*ALPHA); h.h[5]=(_Float16)(c.y*ALPHA);
  h.h[6]=(_Float16)(c.z*ALPHA); h.h[7]=(_Float16)(c.w*ALPHA);
  hi[j] = make_uint4(h.u[0],h.u[1],h.u[2],h.u[3]);
}

// =====================================================================
// v21 attn = v16 (best measured: 96.5us) + hoisted DMA pointers.
// Per tile: vmcnt(0) -> s_barrier -> ISSUE(nt+1 -> buf^1) -> compute(buf).
// 2688 blocks = 56 slices x 8 qb x 6 key-splits; 8 tiles x 32 keys.
// =====================================================================
__launch_bounds__(256, 2)
__global__ void kast_attn21(const ushort* __restrict__ khi, const ushort* __restrict__ mkhi,
                            const float* __restrict__ V_, const float* __restrict__ MV_,
                            float* __restrict__ part) {
  __shared__ uint8_t KB[2][16384];    // [buf][32 keys x 256 f16], XOR-swizzled granules
  __shared__ float vlds[768];         // 256 keys x 3 f32

  // XCD-aware decode: slice s on XCD s%8; its 48 blocks share that L2
  const int bid = blockIdx.x;          // 0..2687
  const int xcd = bid & 7;
  const int idx = bid >> 3;            // 0..335
  const int grp = idx / 48;            // 0..6
  const int sub = idx - grp*48;        // 0..47
  const int s   = xcd + 8*grp;         // slice 0..55
  const int qb  = sub & 7;             // q-block 0..7
  const int ks  = sub >> 3;            // key-split 0..5
  const int b = s / 7, t = s % 7;

  const uint8_t* kh8; const float* vbase;
  if (ks < 4){
    size_t row0 = (size_t)((b*8 + t)*1024 + ks*256);
    kh8 = (const uint8_t*)khi + row0*512;
    vbase = V_ + row0*3;
  } else {
    size_t row0 = (size_t)((b*8 + t)*512 + (ks-4)*256);
    kh8 = (const uint8_t*)mkhi + row0*512;
    vbase = MV_ + row0*3;
  }

  const int tid = threadIdx.x;
  const int w = tid >> 6, l = tid & 63;
  const int lj = l & 15, lq = l >> 4;
  const int qrow0 = qb*128 + w*32;

  // ---- stage V (256 x 3 f32) once ----
  for (int i = tid; i < 768; i += 256) vlds[i] = vbase[i];

  // ---- Q fragments: b128 loads from pre-converted plane ----
  const uint8_t* q8 = (const uint8_t*)khi + (size_t)((b*8 + t + 1)*1024)*512;
  f16x8 qh[2][8];
#pragma unroll
  for (int rt=0; rt<2; rt++){
    const uint8_t* qr = q8 + (size_t)(qrow0 + rt*16 + lj)*512 + lq*16;
#pragma unroll
    for (int kc=0; kc<8; kc++)
      qh[rt][kc] = *(const f16x8*)(qr + kc*64);
  }

  // per-lane online-softmax state (log2 domain, deferred max)
  float m[2][4], ssum[2][4], o[2][4][3];
#pragma unroll
  for (int rt=0;rt<2;rt++)
#pragma unroll
    for (int r=0;r<4;r++){
      m[rt][r]=-1e30f; ssum[rt][r]=0.f;
      o[rt][r][0]=0.f; o[rt][r][1]=0.f; o[rt][r][2]=0.f;
    }

  // DMA: wave stages 8 rows/tile = 4 glds16. per-lane source row = w*8+i*2+(l>>5),
  // granule sg = l&31, pre-swizzled g^(row&7) -> LDS XOR-swizzled, dest linear.
  // HOISTED: 4 per-lane global pointers advanced +16KB/tile (no per-tile addr math).
  const int sg = l & 31;
  const int rsub = l >> 5;
  const int r0 = (w<<3) + rsub;        // i_=0 row
  const uint8_t* gp0 = kh8 + (size_t)(r0    )*512 + (size_t)((sg ^ ((r0  )&7))<<4);
  const uint8_t* gp1 = kh8 + (size_t)(r0 + 2)*512 + (size_t)((sg ^ ((r0+2)&7))<<4);
  const uint8_t* gp2 = kh8 + (size_t)(r0 + 4)*512 + (size_t)((sg ^ ((r0+4)&7))<<4);
  const uint8_t* gp3 = kh8 + (size_t)(r0 + 6)*512 + (size_t)((sg ^ ((r0+6)&7))<<4);
  const uint32_t db0 = (uint32_t)((w<<3)    )*512;
  const uint32_t db1 = (uint32_t)((w<<3) + 2)*512;
  const uint32_t db2 = (uint32_t)((w<<3) + 4)*512;
  const uint32_t db3 = (uint32_t)((w<<3) + 6)*512;

  #define ISSUE(P) do{                         \
    glds16(gp0, &KB[(P)][db0]);                \
    glds16(gp1, &KB[(P)][db1]);                \
    glds16(gp2, &KB[(P)][db2]);                \
    glds16(gp3, &KB[(P)][db3]);                \
    gp0 += 16384; gp1 += 16384;                \
    gp2 += 16384; gp3 += 16384;                \
  }while(0)

  // prologue: tile 0 -> buf 0; full sync also covers V-staging ds_writes
  ISSUE(0);
  __syncthreads();

  for (int nt=0; nt<8; nt++){
    const int cur = nt & 1;
    asm volatile("s_waitcnt vmcnt(0)" ::: "memory");   // my tile-nt DMA landed
    asm volatile("s_barrier" ::: "memory");            // => ALL waves' tile-nt landed;
                                                       //    all reads of buf^1 (iter nt-1) done
    if (nt < 7) ISSUE(cur^1);                          // full compute phase to land

    // ---- MFMA: S = Qh*Kh (log2 domain) ----
    f32x4 acc[2][2];
#pragma unroll
    for (int rt=0;rt<2;rt++){ acc[rt][0]=(f32x4){0,0,0,0}; acc[rt][1]=(f32x4){0,0,0,0}; }

    const int sx = (l&7)<<4;
    __builtin_amdgcn_s_setprio(1);
#pragma unroll
    for (int ct=0;ct<2;ct++){
      const uint8_t* rb = &KB[cur][(ct*16 + lj)*512];
#pragma unroll
      for (int kc=0;kc<8;kc++){
        int bo = (kc*64 + (lq<<4)) ^ sx;
        f16x8 bh = *(const f16x8*)(rb + bo);
        acc[0][ct] = MFMA_F16(qh[0][kc], bh, acc[0][ct]);
        acc[1][ct] = MFMA_F16(qh[1][kc], bh, acc[1][ct]);
      }
    }
    __builtin_amdgcn_s_setprio(0);

    // ---- softmax, exp2 domain with deferred max (THR=24) + PV ----
    float vv[2][3];
#pragma unroll
    for (int ct=0;ct<2;ct++){
      int c = (nt*32 + ct*16 + lj)*3;
      vv[ct][0]=vlds[c]; vv[ct][1]=vlds[c+1]; vv[ct][2]=vlds[c+2];
    }
    float pm[2][4];
    float need = -1e30f;
#pragma unroll
    for (int rt=0;rt<2;rt++)
#pragma unroll
      for (int r=0;r<4;r++){
        pm[rt][r] = fmaxf(acc[rt][0][r], acc[rt][1][r]);
        need = fmaxf(need, pm[rt][r] - m[rt][r]);
      }
    if (need > 24.f){      // fires at tile 0 and rarely after: rescale
#pragma unroll
      for (int rt=0;rt<2;rt++)
#pragma unroll
        for (int r=0;r<4;r++){
          float mn = fmaxf(m[rt][r], pm[rt][r]);
          float sc = EXP2R(m[rt][r] - mn);
          ssum[rt][r] *= sc;
          o[rt][r][0] *= sc; o[rt][r][1] *= sc; o[rt][r][2] *= sc;
          m[rt][r] = mn;
        }
    }
#pragma unroll
    for (int rt=0;rt<2;rt++)
#pragma unroll
      for (int r=0;r<4;r++){
        float p0 = EXP2R(acc[rt][0][r] - m[rt][r]);
        float p1 = EXP2R(acc[rt][1][r] - m[rt][r]);
        ssum[rt][r] += p0 + p1;
        o[rt][r][0] += p0*vv[0][0] + p1*vv[1][0];
        o[rt][r][1] += p0*vv[0][1] + p1*vv[1][1];
        o[rt][r][2] += p0*vv[0][2] + p1*vv[1][2];
      }
  } // nt

  // ---- merge 16 lanes (lj) per row, write partial (m,s,o) ----
#pragma unroll
  for (int rt=0;rt<2;rt++)
#pragma unroll
    for (int r=0;r<4;r++){
      float mm = m[rt][r];
      mm = fmaxf(mm, __shfl_xor(mm,1));
      mm = fmaxf(mm, __shfl_xor(mm,2));
      mm = fmaxf(mm, __shfl_xor(mm,4));
      mm = fmaxf(mm, __shfl_xor(mm,8));
      float f = EXP2R(m[rt][r]-mm);
      float sl = ssum[rt][r]*f;
      float o0=o[rt][r][0]*f, o1=o[rt][r][1]*f, o2=o[rt][r][2]*f;
      sl += __shfl_xor(sl,1); sl += __shfl_xor(sl,2); sl += __shfl_xor(sl,4); sl += __shfl_xor(sl,8);
      o0 += __shfl_xor(o0,1); o0 += __shfl_xor(o0,2); o0 += __shfl_xor(o0,4); o0 += __shfl_xor(o0,8);
      o1 += __shfl_xor(o1,1); o1 += __shfl_xor(o1,2); o1 += __shfl_xor(o1,4); o1 += __shfl_xor(o1,8);
      o2 += __shfl_xor(o2,1); o2 += __shfl_xor(o2,2); o2 += __shfl_xor(o2,4); o2 += __shfl_xor(o2,8);
      if (lj == 0){
        int prow = qrow0 + rt*16 + lq*4 + r;
        float* pp = part + ((size_t)(s*6 + ks)*1024 + prow)*5;
        pp[0]=mm; pp[1]=sl; pp[2]=o0; pp[3]=o1; pp[4]=o2;
      }
    }
  #undef ISSUE
}

// merge 6 partials per q-row (4 K-parts, 2 M-parts) -> blended output
__global__ void kast_merge6(const float* __restrict__ part, float* __restrict__ OUT_){
  int r = blockIdx.x*256 + threadIdx.x;   // 0..57343
  if (r >= 56*1024) return;
  int s = r >> 10, row = r & 1023;
  const float* p[6];
#pragma unroll
  for (int i=0;i<6;i++) p[i] = part + ((size_t)(s*6+i)*1024 + row)*5;
  // K-attn: parts 0..3
  float M1 = fmaxf(fmaxf(p[0][0], p[1][0]), fmaxf(p[2][0], p[3][0]));
  float sK = 0.f, oK0 = 0.f, oK1 = 0.f, oK2 = 0.f;
#pragma unroll
  for (int i=0;i<4;i++){
    float e = EXP2R(p[i][0]-M1);
    sK += p[i][1]*e; oK0 += p[i][2]*e; oK1 += p[i][3]*e; oK2 += p[i][4]*e;
  }
  // M-attn: parts 4..5
  float M2 = fmaxf(p[4][0], p[5][0]);
  float e0 = EXP2R(p[4][0]-M2), e1 = EXP2R(p[5][0]-M2);
  float sM = p[4][1]*e0 + p[5][1]*e1;
  float w1 = 0.8f / sK;
  float w2 = 0.2f / sM;
  float* op = OUT_ + (size_t)(s*1024 + row)*3;
  op[0] = oK0*w1 + (p[4][2]*e0 + p[5][2]*e1)*w2;
  op[1] = oK1*w1 + (p[4][3]*e0 + p[5][3]*e1)*w2;
  op[2] = oK2*w1 + (p[4][4]*e0 + p[5][4]*e1)*w2;
}

// =====================================================================
// Fallback (round-2 passing kernel) if ws too small
// =====================================================================
__launch_bounds__(256, 2)
__global__ void kast_attn_fb(const float* __restrict__ K_, const float* __restrict__ V_,
                             const float* __restrict__ MK_, const float* __restrict__ MV_,
                             float* __restrict__ OUT_) {
  __shared__ char KhB[64*512];
  __shared__ char KlB[64*512];
  __shared__ float vlds[192];

  const int bid = blockIdx.x;
  const int s  = ((bid>>6)<<3) | (bid & 7);
  const int qb = (bid>>3) & 7;
  const int b = s / 7, t = s % 7;
  const float* qptr = K_ + (size_t)((b*8 + t + 1) * 1024) * 256;
  const float* k1   = K_ + (size_t)((b*8 + t) * 1024) * 256;
  const float* v1   = V_ + (size_t)((b*8 + t) * 1024) * 3;
  const float* k2   = MK_ + (size_t)((b*8 + t) * 512) * 256;
  const float* v2   = MV_ + (size_t)((b*8 + t) * 512) * 3;
  float* outp = OUT_ + (size_t)((b*7 + t) * 1024) * 3;

  const int tid = threadIdx.x;
  const int w = tid >> 6, l = tid & 63;
  const int lj = l & 15, lq = l >> 4;
  const int qrow0 = qb*128 + w*32;

  bf16x8 qh[2][8], ql[2][8];
#pragma unroll
  for (int rt=0; rt<2; rt++){
    const float* qr = qptr + (size_t)(qrow0 + rt*16 + lj)*256 + lq*8;
#pragma unroll
    for (int kc=0; kc<8; kc++){
      float4 a = *(const float4*)(qr + kc*32);
      float4 c = *(const float4*)(qr + kc*32 + 4);
      union { uint32_t d[4]; bf16x8 v; } hh, ll;
      split_pair(a.x, a.y, hh.d[0], ll.d[0]);
      split_pair(a.z, a.w, hh.d[1], ll.d[1]);
      split_pair(c.x, c.y, hh.d[2], ll.d[2]);
      split_pair(c.z, c.w, hh.d[3], ll.d[3]);
      qh[rt][kc]=hh.v; ql[rt][kc]=ll.v;
    }
  }

  for (int ph=0; ph<2; ph++){
    const float* ks = ph ? k2 : k1;
    const float* vs = ph ? v2 : v1;
    const int ntiles = ph ? 8 : 16;
    float m[2][4], ssum[2][4], o[2][4][3];
#pragma unroll
    for (int rt=0;rt<2;rt++)
#pragma unroll
      for (int r=0;r<4;r++){
        m[rt][r]=-1e30f; ssum[rt][r]=0.f;
        o[rt][r][0]=0.f; o[rt][r][1]=0.f; o[rt][r][2]=0.f;
      }

    for (int nt=0; nt<ntiles; nt++){
      __syncthreads();
      const float* kt = ks + (size_t)nt*64*256;
#pragma unroll 4
      for (int i=0;i<16;i++){
        int f4i = tid + i*256;
        int row = f4i >> 6;
        int col4 = f4i & 63;
        float4 x = *(const float4*)(kt + row*256 + col4*4);
        uint32_t hp0,lp0,hp1,lp1;
        split_pair(x.x,x.y,hp0,lp0);
        split_pair(x.z,x.w,hp1,lp1);
        int boff = row*512 + ((col4*8) ^ ((row&7)<<4));
        *(uint2*)(KhB + boff) = make_uint2(hp0,hp1);
        *(uint2*)(KlB + boff) = make_uint2(lp0,lp1);
      }
      if (tid < 192) vlds[tid] = vs[nt*192 + tid];
      __syncthreads();

      f32x4 acc[2][4];
#pragma unroll
      for (int rt=0;rt<2;rt++)
#pragma unroll
        for (int ct=0;ct<4;ct++)
          acc[rt][ct] = (f32x4){0.f,0.f,0.f,0.f};

      const int sx = (l&7)<<4;
#pragma unroll
      for (int ct=0;ct<4;ct++){
        const char* rbh = KhB + (ct*16 + lj)*512;
        const char* rbl = KlB + (ct*16 + lj)*512;
#pragma unroll
        for (int kc=0;kc<8;kc++){
          int bo = (kc*64 + (lq<<4)) ^ sx;
          bf16x8 bh = *(const bf16x8*)(rbh + bo);
          bf16x8 bl = *(const bf16x8*)(rbl + bo);
          acc[0][ct] = MFMA_BF16(qh[0][kc], bh, acc[0][ct]);
          acc[1][ct] = MFMA_BF16(qh[1][kc], bh, acc[1][ct]);
          acc[0][ct] = MFMA_BF16(qh[0][kc], bl, acc[0][ct]);
          acc[1][ct] = MFMA_BF16(qh[1][kc], bl, acc[1][ct]);
          acc[0][ct] = MFMA_BF16(ql[0][kc], bh, acc[0][ct]);
          acc[1][ct] = MFMA_BF16(ql[1][kc], bh, acc[1][ct]);
        }
      }

      float vv[4][3];
#pragma unroll
      for (int ct=0;ct<4;ct++){
        int c = (ct*16 + lj)*3;
        vv[ct][0]=vlds[c]; vv[ct][1]=vlds[c+1]; vv[ct][2]=vlds[c+2];
      }
#pragma unroll
      for (int rt=0;rt<2;rt++)
#pragma unroll
        for (int r=0;r<4;r++){
          float s0=acc[rt][0][r], s1=acc[rt][1][r], s2=acc[rt][2][r], s3=acc[rt][3][r];
          float tmax = fmaxf(fmaxf(s0,s1),fmaxf(s2,s3));
          float mo = m[rt][r];
          float mn = fmaxf(mo, tmax);
          float sc = __expf(mo - mn);
          float p0=__expf(s0-mn), p1=__expf(s1-mn), p2=__expf(s2-mn), p3=__expf(s3-mn);
          ssum[rt][r] = ssum[rt][r]*sc + ((p0+p1)+(p2+p3));
          o[rt][r][0] = o[rt][r][0]*sc + (p0*vv[0][0]+p1*vv[1][0]) + (p2*vv[2][0]+p3*vv[3][0]);
          o[rt][r][1] = o[rt][r][1]*sc + (p0*vv[0][1]+p1*vv[1][1]) + (p2*vv[2][1]+p3*vv[3][1]);
          o[rt][r][2] = o[rt][r][2]*sc + (p0*vv[0][2]+p1*vv[1][2]) + (p2*vv[2][2]+p3*vv[3][2]);
          m[rt][r]=mn;
        }
    }

    const float coef = ph ? 0.2f : 0.8f;
#pragma unroll
    for (int rt=0;rt<2;rt++)
#pragma unroll
      for (int r=0;r<4;r++){
        float mm = m[rt][r];
        mm = fmaxf(mm, __shfl_xor(mm,1));
        mm = fmaxf(mm, __shfl_xor(mm,2));
        mm = fmaxf(mm, __shfl_xor(mm,4));
        mm = fmaxf(mm, __shfl_xor(mm,8));
        float f = __expf(m[rt][r]-mm);
        float sl = ssum[rt][r]*f;
        float o0=o[rt][r][0]*f, o1=o[rt][r][1]*f, o2=o[rt][r][2]*f;
        sl += __shfl_xor(sl,1); sl += __shfl_xor(sl,2); sl += __shfl_xor(sl,4); sl += __shfl_xor(sl,8);
        o0 += __shfl_xor(o0,1); o0 += __shfl_xor(o0,2); o0 += __shfl_xor(o0,4); o0 += __shfl_xor(o0,8);
        o1 += __shfl_xor(o1,1); o1 += __shfl_xor(o1,2); o1 += __shfl_xor(o1,4); o1 += __shfl_xor(o1,8);
        o2 += __shfl_xor(o2,1); o2 += __shfl_xor(o2,2); o2 += __shfl_xor(o2,4); o2 += __shfl_xor(o2,8);
        if (lj == 0){
          int row = qrow0 + rt*16 + lq*4 + r;
          float* op = outp + (size_t)row*3;
          float invs = coef / sl;
          if (ph==0){ op[0]=o0*invs; op[1]=o1*invs; op[2]=o2*invs; }
          else      { op[0]+=o0*invs; op[1]+=o1*invs; op[2]+=o2*invs; }
        }
      }
  }
}

// ground truth = v[:,1:] (second output, exact copy)
__global__ void kast_gt(const float* __restrict__ V_, float* __restrict__ OUT_){
  int s = blockIdx.x; int b = s/7, t = s%7;
  const float4* src = (const float4*)(V_ + (size_t)(b*8+t+1)*3072);
  float4* dst = (float4*)(OUT_ + 172032 + (size_t)s*3072);
  for (int i=threadIdx.x; i<768; i+=256) dst[i] = src[i];
}

extern "C" void kernel_launch(void* const* d_in, const int* in_sizes, int n_in,
                              void* d_out, int out_size, void* d_ws, size_t ws_size,
                              hipStream_t stream) {
  (void)in_sizes; (void)n_in; (void)out_size;
  const float* K_  = (const float*)d_in[0];
  const float* V_  = (const float*)d_in[1];
  const float* MK_ = (const float*)d_in[2];
  const float* MV_ = (const float*)d_in[3];
  float* out = (float*)d_out;

  // ws layout (bytes): khi 33.55M | mkhi 16.78M | partials 6.88M
  const size_t NEED = 57212928;
  if (ws_size >= NEED){
    uint8_t* w8 = (uint8_t*)d_ws;
    ushort* khi  = (ushort*)(w8);
    ushort* mkhi = (ushort*)(w8 + 33554432);
    float*  part = (float*)(w8 + 50331648);
    hipLaunchKernelGGL(kast_cvt3, dim3(12288), dim3(256), 0, stream, K_, MK_,
                       (uint4*)khi, (uint4*)mkhi);
    hipLaunchKernelGGL(kast_attn21, dim3(2688), dim3(256), 0, stream, khi, mkhi, V_, MV_, part);
    hipLaunchKernelGGL(kast_merge6, dim3(224),  dim3(256), 0, stream, part, out);
  } else {
    hipLaunchKernelGGL(kast_attn_fb, dim3(448), dim3(256), 0, stream, K_, V_, MK_, MV_, out);
  }
  hipLaunchKernelGGL(kast_gt, dim3(56), dim3(256), 0, stream, V_, out);
}

// Round 23
// 109.265 us; speedup vs baseline: 1.0839x; 1.0323x over previous
//
#include <hip/hip_runtime.h>
#include <stdint.h>

typedef _Float16 f16x8 __attribute__((ext_vector_type(8)));
typedef __bf16 bf16x8 __attribute__((ext_vector_type(8)));
typedef float f32x4 __attribute__((ext_vector_type(4)));

#define MFMA_F16(a,b,c) __builtin_amdgcn_mfma_f32_16x16x32_f16(a,b,c,0,0,0)
#define MFMA_BF16(a,b,c) __builtin_amdgcn_mfma_f32_16x16x32_bf16(a,b,c,0,0,0)
#define ALPHA 1.2011224087864498f   // sqrt(log2(e)); both operands scaled -> S in log2 domain
#define EXP2R(x) __builtin_amdgcn_exp2f(x)   // raw v_exp_f32 (args bounded by defer-max)

// ---------------- helpers ----------------
__device__ __forceinline__ uint32_t f2u(float x){ union{float f;uint32_t u;} c; c.f=x; return c.u; }
__device__ __forceinline__ float u2f(uint32_t u){ union{float f;uint32_t u;} c; c.u=u; return c.f; }

union HU8 { uint32_t u[4]; _Float16 h[8]; f16x8 v; };

// bf16 truncation split (fallback kernel)
__device__ __forceinline__ void split_pair(float x0, float x1, uint32_t& hp, uint32_t& lp){
  uint32_t u0=f2u(x0), u1=f2u(x1);
  uint32_t h0=u0&0xFFFF0000u, h1=u1&0xFFFF0000u;
  hp = (u0>>16) | h1;
  float l0 = x0 - u2f(h0), l1 = x1 - u2f(h1);
  lp = (f2u(l0)>>16) | (f2u(l1)&0xFFFF0000u);
}

// async global->LDS, 16 bytes per lane. LDS dest = wave-uniform base + lane*16.
__device__ __forceinline__ void glds16(const void* g, void* l){
  __builtin_amdgcn_global_load_lds(
      (const __attribute__((address_space(1))) uint32_t*)(uintptr_t)g,
      (__attribute__((address_space(3))) uint32_t*)(uint32_t)(uintptr_t)l,
      16, 0, 0);
}

// =====================================================================
// Pre-pass: ALPHA*x -> f16 RN plane. K: all 8 t (Q needs t=1..7, K-DMA
// t=0..6). m_k: only t=0..6 per batch (t=7 never read), COMPACT layout.
// K: 2097152 x8-units. m_k compact: 8 b x 7 t x 512 x 32 = 917504.
// Total 3014656 -> grid 11776 x 256.
// =====================================================================
__global__ void kast_cvt4(const float* __restrict__ K_, const float* __restrict__ MK_,
                          uint4* __restrict__ khi, uint4* __restrict__ mkhi){
  int i = blockIdx.x*256 + threadIdx.x;     // 0..3014655
  if (i >= 3014656) return;
  const float* src; uint4* hi; size_t j, sj;
  if (i < 2097152){ src = K_;  hi = khi;  j = i; sj = i; }
  else {
    int q = i - 2097152;                    // 0..917503 (8 b x 7 t x 512 x 32)
    int bq = q / 114688;                    // batch 0..7 (114688 = 7*512*32)
    int rq = q - bq*114688;
    src = MK_; hi = mkhi;
    j  = (size_t)q;                         // compact dst (t=7 skipped)
    sj = (size_t)bq*131072 + rq;            // src: 8 t per batch = 131072 x8-units
  }
  const float4* in4 = (const float4*)src;
  float4 a = in4[sj*2], c = in4[sj*2+1];
  HU8 h;
  h.h[0]=(_Float16)(a.x*ALPHA); h.h[1]=(_Float16)(a.y*ALPHA);
  h.h[2]=(_Float16)(a.z*ALPHA); h.h[3]=(_Float16)(a.w*ALPHA);
  h.h[4]=(_Float16)(c.x*ALPHA); h.h[5]=(_Float16)(c.y*ALPHA);
  h.h[6]=(_Float16)(c.z*ALPHA); h.h[7]=(_Float16)(c.w*ALPHA);
  hi[j] = make_uint4(h.u[0],h.u[1],h.u[2],h.u[3]);
}

// =====================================================================
// v23 attn = v21 (best measured) with mkhi in COMPACT layout (7 t/batch).
// Per tile: vmcnt(0) -> s_barrier -> ISSUE -> compute.
// 2688 blocks = 56 slices x 8 qb x 6 key-splits; 8 tiles x 32 keys.
// =====================================================================
__launch_bounds__(256, 2)
__global__ void kast_attn23(const ushort* __restrict__ khi, const ushort* __restrict__ mkhi,
                            const float* __restrict__ V_, const float* __restrict__ MV_,
                            float* __restrict__ part) {
  __shared__ uint8_t KB[2][16384];    // [buf][32 keys x 256 f16], XOR-swizzled granules
  __shared__ float vlds[768];         // 256 keys x 3 f32

  // XCD-aware decode: slice s on XCD s%8; its 48 blocks share that L2
  const int bid = blockIdx.x;          // 0..2687
  const int xcd = bid & 7;
  const int idx = bid >> 3;            // 0..335
  const int grp = idx / 48;            // 0..6
  const int sub = idx - grp*48;        // 0..47
  const int s   = xcd + 8*grp;         // slice 0..55
  const int qb  = sub & 7;             // q-block 0..7
  const int ks  = sub >> 3;            // key-split 0..5
  const int b = s / 7, t = s % 7;

  const uint8_t* kh8; const float* vbase;
  if (ks < 4){
    size_t row0 = (size_t)((b*8 + t)*1024 + ks*256);
    kh8 = (const uint8_t*)khi + row0*512;
    vbase = V_ + row0*3;
  } else {
    // compact m_k layout: batch stride 7*512 rows
    size_t row0 = (size_t)((b*7 + t)*512 + (ks-4)*256);
    kh8 = (const uint8_t*)mkhi + row0*512;
    vbase = MV_ + (size_t)((b*8 + t)*512 + (ks-4)*256)*3;
  }

  const int tid = threadIdx.x;
  const int w = tid >> 6, l = tid & 63;
  const int lj = l & 15, lq = l >> 4;
  const int qrow0 = qb*128 + w*32;

  // ---- stage V (256 x 3 f32) once ----
  for (int i = tid; i < 768; i += 256) vlds[i] = vbase[i];

  // ---- Q fragments: b128 loads from pre-converted plane ----
  const uint8_t* q8 = (const uint8_t*)khi + (size_t)((b*8 + t + 1)*1024)*512;
  f16x8 qh[2][8];
#pragma unroll
  for (int rt=0; rt<2; rt++){
    const uint8_t* qr = q8 + (size_t)(qrow0 + rt*16 + lj)*512 + lq*16;
#pragma unroll
    for (int kc=0; kc<8; kc++)
      qh[rt][kc] = *(const f16x8*)(qr + kc*64);
  }

  // per-lane online-softmax state (log2 domain, deferred max)
  float m[2][4], ssum[2][4], o[2][4][3];
#pragma unroll
  for (int rt=0;rt<2;rt++)
#pragma unroll
    for (int r=0;r<4;r++){
      m[rt][r]=-1e30f; ssum[rt][r]=0.f;
      o[rt][r][0]=0.f; o[rt][r][1]=0.f; o[rt][r][2]=0.f;
    }

  // DMA: wave stages 8 rows/tile = 4 glds16; hoisted per-lane pointers.
  const int sg = l & 31;
  const int rsub = l >> 5;
  const int r0 = (w<<3) + rsub;
  const uint8_t* gp0 = kh8 + (size_t)(r0    )*512 + (size_t)((sg ^ ((r0  )&7))<<4);
  const uint8_t* gp1 = kh8 + (size_t)(r0 + 2)*512 + (size_t)((sg ^ ((r0+2)&7))<<4);
  const uint8_t* gp2 = kh8 + (size_t)(r0 + 4)*512 + (size_t)((sg ^ ((r0+4)&7))<<4);
  const uint8_t* gp3 = kh8 + (size_t)(r0 + 6)*512 + (size_t)((sg ^ ((r0+6)&7))<<4);
  const uint32_t db0 = (uint32_t)((w<<3)    )*512;
  const uint32_t db1 = (uint32_t)((w<<3) + 2)*512;
  const uint32_t db2 = (uint32_t)((w<<3) + 4)*512;
  const uint32_t db3 = (uint32_t)((w<<3) + 6)*512;

  #define ISSUE(P) do{                         \
    glds16(gp0, &KB[(P)][db0]);                \
    glds16(gp1, &KB[(P)][db1]);                \
    glds16(gp2, &KB[(P)][db2]);                \
    glds16(gp3, &KB[(P)][db3]);                \
    gp0 += 16384; gp1 += 16384;                \
    gp2 += 16384; gp3 += 16384;                \
  }while(0)

  // prologue: tile 0 -> buf 0; full sync also covers V-staging ds_writes
  ISSUE(0);
  __syncthreads();

  for (int nt=0; nt<8; nt++){
    const int cur = nt & 1;
    asm volatile("s_waitcnt vmcnt(0)" ::: "memory");   // my tile-nt DMA landed
    asm volatile("s_barrier" ::: "memory");            // all waves' tile-nt landed; prev reads done
    if (nt < 7) ISSUE(cur^1);                          // full compute phase to land

    // ---- MFMA: S = Qh*Kh (log2 domain) ----
    f32x4 acc[2][2];
#pragma unroll
    for (int rt=0;rt<2;rt++){ acc[rt][0]=(f32x4){0,0,0,0}; acc[rt][1]=(f32x4){0,0,0,0}; }

    const int sx = (l&7)<<4;
    __builtin_amdgcn_s_setprio(1);
#pragma unroll
    for (int ct=0;ct<2;ct++){
      const uint8_t* rb = &KB[cur][(ct*16 + lj)*512];
#pragma unroll
      for (int kc=0;kc<8;kc++){
        int bo = (kc*64 + (lq<<4)) ^ sx;
        f16x8 bh = *(const f16x8*)(rb + bo);
        acc[0][ct] = MFMA_F16(qh[0][kc], bh, acc[0][ct]);
        acc[1][ct] = MFMA_F16(qh[1][kc], bh, acc[1][ct]);
      }
    }
    __builtin_amdgcn_s_setprio(0);

    // ---- softmax, exp2 domain with deferred max (THR=24) + PV ----
    float vv[2][3];
#pragma unroll
    for (int ct=0;ct<2;ct++){
      int c = (nt*32 + ct*16 + lj)*3;
      vv[ct][0]=vlds[c]; vv[ct][1]=vlds[c+1]; vv[ct][2]=vlds[c+2];
    }
    float pm[2][4];
    float need = -1e30f;
#pragma unroll
    for (int rt=0;rt<2;rt++)
#pragma unroll
      for (int r=0;r<4;r++){
        pm[rt][r] = fmaxf(acc[rt][0][r], acc[rt][1][r]);
        need = fmaxf(need, pm[rt][r] - m[rt][r]);
      }
    if (need > 24.f){      // fires at tile 0 and rarely after: rescale
#pragma unroll
      for (int rt=0;rt<2;rt++)
#pragma unroll
        for (int r=0;r<4;r++){
          float mn = fmaxf(m[rt][r], pm[rt][r]);
          float sc = EXP2R(m[rt][r] - mn);
          ssum[rt][r] *= sc;
          o[rt][r][0] *= sc; o[rt][r][1] *= sc; o[rt][r][2] *= sc;
          m[rt][r] = mn;
        }
    }
#pragma unroll
    for (int rt=0;rt<2;rt++)
#pragma unroll
      for (int r=0;r<4;r++){
        float p0 = EXP2R(acc[rt][0][r] - m[rt][r]);
        float p1 = EXP2R(acc[rt][1][r] - m[rt][r]);
        ssum[rt][r] += p0 + p1;
        o[rt][r][0] += p0*vv[0][0] + p1*vv[1][0];
        o[rt][r][1] += p0*vv[0][1] + p1*vv[1][1];
        o[rt][r][2] += p0*vv[0][2] + p1*vv[1][2];
      }
  } // nt

  // ---- merge 16 lanes (lj) per row, write partial (m,s,o) ----
#pragma unroll
  for (int rt=0;rt<2;rt++)
#pragma unroll
    for (int r=0;r<4;r++){
      float mm = m[rt][r];
      mm = fmaxf(mm, __shfl_xor(mm,1));
      mm = fmaxf(mm, __shfl_xor(mm,2));
      mm = fmaxf(mm, __shfl_xor(mm,4));
      mm = fmaxf(mm, __shfl_xor(mm,8));
      float f = EXP2R(m[rt][r]-mm);
      float sl = ssum[rt][r]*f;
      float o0=o[rt][r][0]*f, o1=o[rt][r][1]*f, o2=o[rt][r][2]*f;
      sl += __shfl_xor(sl,1); sl += __shfl_xor(sl,2); sl += __shfl_xor(sl,4); sl += __shfl_xor(sl,8);
      o0 += __shfl_xor(o0,1); o0 += __shfl_xor(o0,2); o0 += __shfl_xor(o0,4); o0 += __shfl_xor(o0,8);
      o1 += __shfl_xor(o1,1); o1 += __shfl_xor(o1,2); o1 += __shfl_xor(o1,4); o1 += __shfl_xor(o1,8);
      o2 += __shfl_xor(o2,1); o2 += __shfl_xor(o2,2); o2 += __shfl_xor(o2,4); o2 += __shfl_xor(o2,8);
      if (lj == 0){
        int prow = qrow0 + rt*16 + lq*4 + r;
        float* pp = part + ((size_t)(s*6 + ks)*1024 + prow)*5;
        pp[0]=mm; pp[1]=sl; pp[2]=o0; pp[3]=o1; pp[4]=o2;
      }
    }
  #undef ISSUE
}

// =====================================================================
// merge 6 partials per q-row -> blended output; ALSO copies ground
// truth (v[:,1:]) for its row (fuses the old kast_gt launch).
// =====================================================================
__global__ void kast_merge7(const float* __restrict__ part, const float* __restrict__ V_,
                            float* __restrict__ OUT_){
  int r = blockIdx.x*256 + threadIdx.x;   // 0..57343
  if (r >= 56*1024) return;
  int s = r >> 10, row = r & 1023;
  const float* p[6];
#pragma unroll
  for (int i=0;i<6;i++) p[i] = part + ((size_t)(s*6+i)*1024 + row)*5;
  // K-attn: parts 0..3
  float M1 = fmaxf(fmaxf(p[0][0], p[1][0]), fmaxf(p[2][0], p[3][0]));
  float sK = 0.f, oK0 = 0.f, oK1 = 0.f, oK2 = 0.f;
#pragma unroll
  for (int i=0;i<4;i++){
    float e = EXP2R(p[i][0]-M1);
    sK += p[i][1]*e; oK0 += p[i][2]*e; oK1 += p[i][3]*e; oK2 += p[i][4]*e;
  }
  // M-attn: parts 4..5
  float M2 = fmaxf(p[4][0], p[5][0]);
  float e0 = EXP2R(p[4][0]-M2), e1 = EXP2R(p[5][0]-M2);
  float sM = p[4][1]*e0 + p[5][1]*e1;
  float w1 = 0.8f / sK;
  float w2 = 0.2f / sM;
  float* op = OUT_ + (size_t)r*3;
  op[0] = oK0*w1 + (p[4][2]*e0 + p[5][2]*e1)*w2;
  op[1] = oK1*w1 + (p[4][3]*e0 + p[5][3]*e1)*w2;
  op[2] = oK2*w1 + (p[4][4]*e0 + p[5][4]*e1)*w2;
  // ground truth: v[b, t+1, row] -> OUT[172032 + r*3]
  int b = s / 7, t = s % 7;
  const float* gv = V_ + (size_t)((b*8 + t + 1)*1024 + row)*3;
  float* gp = OUT_ + 172032 + (size_t)r*3;
  gp[0]=gv[0]; gp[1]=gv[1]; gp[2]=gv[2];
}

// =====================================================================
// Fallback (round-2 passing kernel) if ws too small
// =====================================================================
__launch_bounds__(256, 2)
__global__ void kast_attn_fb(const float* __restrict__ K_, const float* __restrict__ V_,
                             const float* __restrict__ MK_, const float* __restrict__ MV_,
                             float* __restrict__ OUT_) {
  __shared__ char KhB[64*512];
  __shared__ char KlB[64*512];
  __shared__ float vlds[192];

  const int bid = blockIdx.x;
  const int s  = ((bid>>6)<<3) | (bid & 7);
  const int qb = (bid>>3) & 7;
  const int b = s / 7, t = s % 7;
  const float* qptr = K_ + (size_t)((b*8 + t + 1) * 1024) * 256;
  const float* k1   = K_ + (size_t)((b*8 + t) * 1024) * 256;
  const float* v1   = V_ + (size_t)((b*8 + t) * 1024) * 3;
  const float* k2   = MK_ + (size_t)((b*8 + t) * 512) * 256;
  const float* v2   = MV_ + (size_t)((b*8 + t) * 512) * 3;
  float* outp = OUT_ + (size_t)((b*7 + t) * 1024) * 3;

  const int tid = threadIdx.x;
  const int w = tid >> 6, l = tid & 63;
  const int lj = l & 15, lq = l >> 4;
  const int qrow0 = qb*128 + w*32;

  bf16x8 qh[2][8], ql[2][8];
#pragma unroll
  for (int rt=0; rt<2; rt++){
    const float* qr = qptr + (size_t)(qrow0 + rt*16 + lj)*256 + lq*8;
#pragma unroll
    for (int kc=0; kc<8; kc++){
      float4 a = *(const float4*)(qr + kc*32);
      float4 c = *(const float4*)(qr + kc*32 + 4);
      union { uint32_t d[4]; bf16x8 v; } hh, ll;
      split_pair(a.x, a.y, hh.d[0], ll.d[0]);
      split_pair(a.z, a.w, hh.d[1], ll.d[1]);
      split_pair(c.x, c.y, hh.d[2], ll.d[2]);
      split_pair(c.z, c.w, hh.d[3], ll.d[3]);
      qh[rt][kc]=hh.v; ql[rt][kc]=ll.v;
    }
  }

  for (int ph=0; ph<2; ph++){
    const float* ks = ph ? k2 : k1;
    const float* vs = ph ? v2 : v1;
    const int ntiles = ph ? 8 : 16;
    float m[2][4], ssum[2][4], o[2][4][3];
#pragma unroll
    for (int rt=0;rt<2;rt++)
#pragma unroll
      for (int r=0;r<4;r++){
        m[rt][r]=-1e30f; ssum[rt][r]=0.f;
        o[rt][r][0]=0.f; o[rt][r][1]=0.f; o[rt][r][2]=0.f;
      }

    for (int nt=0; nt<ntiles; nt++){
      __syncthreads();
      const float* kt = ks + (size_t)nt*64*256;
#pragma unroll 4
      for (int i=0;i<16;i++){
        int f4i = tid + i*256;
        int row = f4i >> 6;
        int col4 = f4i & 63;
        float4 x = *(const float4*)(kt + row*256 + col4*4);
        uint32_t hp0,lp0,hp1,lp1;
        split_pair(x.x,x.y,hp0,lp0);
        split_pair(x.z,x.w,hp1,lp1);
        int boff = row*512 + ((col4*8) ^ ((row&7)<<4));
        *(uint2*)(KhB + boff) = make_uint2(hp0,hp1);
        *(uint2*)(KlB + boff) = make_uint2(lp0,lp1);
      }
      if (tid < 192) vlds[tid] = vs[nt*192 + tid];
      __syncthreads();

      f32x4 acc[2][4];
#pragma unroll
      for (int rt=0;rt<2;rt++)
#pragma unroll
        for (int ct=0;ct<4;ct++)
          acc[rt][ct] = (f32x4){0.f,0.f,0.f,0.f};

      const int sx = (l&7)<<4;
#pragma unroll
      for (int ct=0;ct<4;ct++){
        const char* rbh = KhB + (ct*16 + lj)*512;
        const char* rbl = KlB + (ct*16 + lj)*512;
#pragma unroll
        for (int kc=0;kc<8;kc++){
          int bo = (kc*64 + (lq<<4)) ^ sx;
          bf16x8 bh = *(const bf16x8*)(rbh + bo);
          bf16x8 bl = *(const bf16x8*)(rbl + bo);
          acc[0][ct] = MFMA_BF16(qh[0][kc], bh, acc[0][ct]);
          acc[1][ct] = MFMA_BF16(qh[1][kc], bh, acc[1][ct]);
          acc[0][ct] = MFMA_BF16(qh[0][kc], bl, acc[0][ct]);
          acc[1][ct] = MFMA_BF16(qh[1][kc], bl, acc[1][ct]);
          acc[0][ct] = MFMA_BF16(ql[0][kc], bh, acc[0][ct]);
          acc[1][ct] = MFMA_BF16(ql[1][kc], bh, acc[1][ct]);
        }
      }

      float vv[4][3];
#pragma unroll
      for (int ct=0;ct<4;ct++){
        int c = (ct*16 + lj)*3;
        vv[ct][0]=vlds[c]; vv[ct][1]=vlds[c+1]; vv[ct][2]=vlds[c+2];
      }
#pragma unroll
      for (int rt=0;rt<2;rt++)
#pragma unroll
        for (int r=0;r<4;r++){
          float s0=acc[rt][0][r], s1=acc[rt][1][r], s2=acc[rt][2][r], s3=acc[rt][3][r];
          float tmax = fmaxf(fmaxf(s0,s1),fmaxf(s2,s3));
          float mo = m[rt][r];
          float mn = fmaxf(mo, tmax);
          float sc = __expf(mo - mn);
          float p0=__expf(s0-mn), p1=__expf(s1-mn), p2=__expf(s2-mn), p3=__expf(s3-mn);
          ssum[rt][r] = ssum[rt][r]*sc + ((p0+p1)+(p2+p3));
          o[rt][r][0] = o[rt][r][0]*sc + (p0*vv[0][0]+p1*vv[1][0]) + (p2*vv[2][0]+p3*vv[3][0]);
          o[rt][r][1] = o[rt][r][1]*sc + (p0*vv[0][1]+p1*vv[1][1]) + (p2*vv[2][1]+p3*vv[3][1]);
          o[rt][r][2] = o[rt][r][2]*sc + (p0*vv[0][2]+p1*vv[1][2]) + (p2*vv[2][2]+p3*vv[3][2]);
          m[rt][r]=mn;
        }
    }

    const float coef = ph ? 0.2f : 0.8f;
#pragma unroll
    for (int rt=0;rt<2;rt++)
#pragma unroll
      for (int r=0;r<4;r++){
        float mm = m[rt][r];
        mm = fmaxf(mm, __shfl_xor(mm,1));
        mm = fmaxf(mm, __shfl_xor(mm,2));
        mm = fmaxf(mm, __shfl_xor(mm,4));
        mm = fmaxf(mm, __shfl_xor(mm,8));
        float f = __expf(m[rt][r]-mm);
        float sl = ssum[rt][r]*f;
        float o0=o[rt][r][0]*f, o1=o[rt][r][1]*f, o2=o[rt][r][2]*f;
        sl += __shfl_xor(sl,1); sl += __shfl_xor(sl,2); sl += __shfl_xor(sl,4); sl += __shfl_xor(sl,8);
        o0 += __shfl_xor(o0,1); o0 += __shfl_xor(o0,2); o0 += __shfl_xor(o0,4); o0 += __shfl_xor(o0,8);
        o1 += __shfl_xor(o1,1); o1 += __shfl_xor(o1,2); o1 += __shfl_xor(o1,4); o1 += __shfl_xor(o1,8);
        o2 += __shfl_xor(o2,1); o2 += __shfl_xor(o2,2); o2 += __shfl_xor(o2,4); o2 += __shfl_xor(o2,8);
        if (lj == 0){
          int row = qrow0 + rt*16 + lq*4 + r;
          float* op = outp + (size_t)row*3;
          float invs = coef / sl;
          if (ph==0){ op[0]=o0*invs; op[1]=o1*invs; op[2]=o2*invs; }
          else      { op[0]+=o0*invs; op[1]+=o1*invs; op[2]+=o2*invs; }
        }
      }
  }
}

// ground truth = v[:,1:] (second output, exact copy) — fallback path only
__global__ void kast_gt(const float* __restrict__ V_, float* __restrict__ OUT_){
  int s = blockIdx.x; int b = s/7, t = s%7;
  const float4* src = (const float4*)(V_ + (size_t)(b*8+t+1)*3072);
  float4* dst = (float4*)(OUT_ + 172032 + (size_t)s*3072);
  for (int i=threadIdx.x; i<768; i+=256) dst[i] = src[i];
}

extern "C" void kernel_launch(void* const* d_in, const int* in_sizes, int n_in,
                              void* d_out, int out_size, void* d_ws, size_t ws_size,
                              hipStream_t stream) {
  (void)in_sizes; (void)n_in; (void)out_size;
  const float* K_  = (const float*)d_in[0];
  const float* V_  = (const float*)d_in[1];
  const float* MK_ = (const float*)d_in[2];
  const float* MV_ = (const float*)d_in[3];
  float* out = (float*)d_out;

  // ws layout (bytes): khi 33.55M | mkhi(compact 7t, 8b) 14.68M | partials 6.88M
  const size_t NEED = 33554432 + 14680064 + 6881280;  // 55115776
  if (ws_size >= NEED){
    uint8_t* w8 = (uint8_t*)d_ws;
    ushort* khi  = (ushort*)(w8);
    ushort* mkhi = (ushort*)(w8 + 33554432);
    float*  part = (float*)(w8 + 48234496);
    hipLaunchKernelGGL(kast_cvt4, dim3(11776), dim3(256), 0, stream, K_, MK_,
                       (uint4*)khi, (uint4*)mkhi);
    hipLaunchKernelGGL(kast_attn23, dim3(2688), dim3(256), 0, stream, khi, mkhi, V_, MV_, part);
    hipLaunchKernelGGL(kast_merge7, dim3(224),  dim3(256), 0, stream, part, V_, out);
  } else {
    hipLaunchKernelGGL(kast_attn_fb, dim3(448), dim3(256), 0, stream, K_, V_, MK_, MV_, out);
    hipLaunchKernelGGL(kast_gt, dim3(56), dim3(256), 0, stream, V_, out);
  }
}